// Round 1
// baseline (1686.227 us; speedup 1.0000x reference)
//
#include <hip/hip_runtime.h>

#define B_   16
#define CIN  128
#define NPT  2048
#define COUT 256
#define KNN  20
#define EPS  1e-5f

// workspace byte offsets
#define SQ_OFF   0ull                          // 32768 f
#define IDX_OFF  131072ull                     // 16*2048*20 i32
#define UT_OFF   2752512ull                    // 16*2048*256 f
#define VT_OFF   36306944ull                   // 16*2048*256 f
#define GS_OFF   69861376ull                   // 2*256 double
#define ST_OFF   69865472ull                   // 2*256 f

// ---------------------------------------------------------------- sq[b][n]
__global__ void sq_kernel(const float* __restrict__ x, float* __restrict__ sq) {
    int gid = blockIdx.x * 256 + threadIdx.x;          // 32768 total
    int b = gid >> 11, n = gid & 2047;
    const float* xp = x + (size_t)b * CIN * NPT + n;
    float acc = 0.f;
    #pragma unroll
    for (int c = 0; c < CIN; ++c) { float v = xp[c * NPT]; acc += v * v; }
    sq[gid] = acc;
}

// ------------------------------------------------- u/v GEMM: uT/vT[b][n][o]
// u = (W1-W2) @ x  (central term), v = W2 @ x (neighbor term)
__global__ __launch_bounds__(256) void uv_gemm(const float* __restrict__ x,
                                               const float* __restrict__ W,
                                               float* __restrict__ uT,
                                               float* __restrict__ vT) {
    __shared__ float Ax[32 * 64];   // [cz][ni]
    __shared__ float Bu[32 * 68];   // [cz][oj], pad 68
    __shared__ float Bv[32 * 68];

    const int b  = blockIdx.z;
    const int n0 = blockIdx.x * 64;
    const int o0 = blockIdx.y * 64;
    const int t  = threadIdx.x;
    const int tx = t & 15, ty = t >> 4;
    const float* xb = x + (size_t)b * CIN * NPT;

    float au[4][4], av_[4][4];
    #pragma unroll
    for (int i = 0; i < 4; ++i)
        #pragma unroll
        for (int j = 0; j < 4; ++j) { au[i][j] = 0.f; av_[i][j] = 0.f; }

    #pragma unroll 1
    for (int kc = 0; kc < 4; ++kc) {
        const int c0 = kc * 32;
        __syncthreads();
        #pragma unroll
        for (int e = 0; e < 8; ++e) {            // x tile: 32c x 64n
            int ii = e * 256 + t;
            int cz = ii >> 6, ni = ii & 63;
            Ax[ii] = xb[(size_t)(c0 + cz) * NPT + n0 + ni];
        }
        #pragma unroll
        for (int e = 0; e < 8; ++e) {            // W tiles: 32c x 64o
            int ii = e * 256 + t;
            int cz = ii & 31, oj = ii >> 5;
            float w1 = W[(size_t)(o0 + oj) * 256 + c0 + cz];
            float w2 = W[(size_t)(o0 + oj) * 256 + 128 + c0 + cz];
            Bu[cz * 68 + oj] = w1 - w2;
            Bv[cz * 68 + oj] = w2;
        }
        __syncthreads();
        #pragma unroll 8
        for (int cz = 0; cz < 32; ++cz) {
            const float4 a4 = *(const float4*)&Ax[(cz << 6) + (tx << 2)];
            float bu0 = Bu[cz * 68 + (ty << 2) + 0], bv0 = Bv[cz * 68 + (ty << 2) + 0];
            float bu1 = Bu[cz * 68 + (ty << 2) + 1], bv1 = Bv[cz * 68 + (ty << 2) + 1];
            float bu2 = Bu[cz * 68 + (ty << 2) + 2], bv2 = Bv[cz * 68 + (ty << 2) + 2];
            float bu3 = Bu[cz * 68 + (ty << 2) + 3], bv3 = Bv[cz * 68 + (ty << 2) + 3];
            au[0][0] += a4.x * bu0; au[0][1] += a4.x * bu1; au[0][2] += a4.x * bu2; au[0][3] += a4.x * bu3;
            au[1][0] += a4.y * bu0; au[1][1] += a4.y * bu1; au[1][2] += a4.y * bu2; au[1][3] += a4.y * bu3;
            au[2][0] += a4.z * bu0; au[2][1] += a4.z * bu1; au[2][2] += a4.z * bu2; au[2][3] += a4.z * bu3;
            au[3][0] += a4.w * bu0; au[3][1] += a4.w * bu1; au[3][2] += a4.w * bu2; au[3][3] += a4.w * bu3;
            av_[0][0] += a4.x * bv0; av_[0][1] += a4.x * bv1; av_[0][2] += a4.x * bv2; av_[0][3] += a4.x * bv3;
            av_[1][0] += a4.y * bv0; av_[1][1] += a4.y * bv1; av_[1][2] += a4.y * bv2; av_[1][3] += a4.y * bv3;
            av_[2][0] += a4.z * bv0; av_[2][1] += a4.z * bv1; av_[2][2] += a4.z * bv2; av_[2][3] += a4.z * bv3;
            av_[3][0] += a4.w * bv0; av_[3][1] += a4.w * bv1; av_[3][2] += a4.w * bv2; av_[3][3] += a4.w * bv3;
        }
    }
    #pragma unroll
    for (int i = 0; i < 4; ++i) {
        int n = n0 + (tx << 2) + i;
        size_t base = ((size_t)b * NPT + n) * COUT + o0 + (ty << 2);
        float4 u4 = {au[i][0], au[i][1], au[i][2], au[i][3]};
        float4 v4 = {av_[i][0], av_[i][1], av_[i][2], av_[i][3]};
        *(float4*)&uT[base] = u4;
        *(float4*)&vT[base] = v4;
    }
}

// ---------------------------------------------------------------- KNN
// fp32 tiled distance GEMM + per-lane top-20 (4 lanes/query over disjoint
// m-subsets) + fp64 refinement of all 80 candidates -> exact top-20 set.
__global__ __launch_bounds__(256, 2) void knn_kernel(const float* __restrict__ x,
                                                     const float* __restrict__ sqn,
                                                     int* __restrict__ knn_out) {
    __shared__ float sm[16768];            // 67072 B
    float* Xq  = sm;                       // [128][64]
    float* Xm  = sm + 8192;                // [64][64]
    float* Dt  = sm + 12288;               // [64][68]
    float* sqq = sm + 16640;               // [64]
    float* sqm = sm + 16704;               // [64]

    const int b  = blockIdx.y;
    const int q0 = blockIdx.x * 64;
    const int t  = threadIdx.x;
    const int tx = t & 15, ty = t >> 4;    // GEMM mapping
    const int qi = t >> 2,  r = t & 3;     // top-k mapping
    const float* xb = x + (size_t)b * CIN * NPT;

    #pragma unroll
    for (int e = 0; e < 32; ++e) {         // Xq: 128c x 64q, persistent
        int ii = e * 256 + t;
        int c = ii >> 6, n = ii & 63;
        Xq[ii] = xb[(size_t)c * NPT + q0 + n];
    }
    if (t < 64) sqq[t] = sqn[b * NPT + q0 + t];

    float bd[KNN]; int bi[KNN];
    #pragma unroll
    for (int i = 0; i < KNN; ++i) { bd[i] = 3e38f; bi[i] = 0; }

    #pragma unroll 1
    for (int mt = 0; mt < 32; ++mt) {
        const int m0 = mt * 64;
        float acc[4][4];
        #pragma unroll
        for (int i = 0; i < 4; ++i)
            #pragma unroll
            for (int j = 0; j < 4; ++j) acc[i][j] = 0.f;

        #pragma unroll
        for (int kc = 0; kc < 2; ++kc) {
            __syncthreads();
            #pragma unroll
            for (int e = 0; e < 16; ++e) {   // Xm chunk: 64c x 64m
                int ii = e * 256 + t;
                int c = ii >> 6, mi = ii & 63;
                Xm[ii] = xb[(size_t)(kc * 64 + c) * NPT + m0 + mi];
            }
            if (kc == 0 && t < 64) sqm[t] = sqn[b * NPT + m0 + t];
            __syncthreads();
            #pragma unroll 8
            for (int c = 0; c < 64; ++c) {
                const float4 a4 = *(const float4*)&Xq[((kc * 64 + c) << 6) + (tx << 2)];
                const float4 b4 = *(const float4*)&Xm[(c << 6) + (ty << 2)];
                acc[0][0] += a4.x * b4.x; acc[0][1] += a4.x * b4.y; acc[0][2] += a4.x * b4.z; acc[0][3] += a4.x * b4.w;
                acc[1][0] += a4.y * b4.x; acc[1][1] += a4.y * b4.y; acc[1][2] += a4.y * b4.z; acc[1][3] += a4.y * b4.w;
                acc[2][0] += a4.z * b4.x; acc[2][1] += a4.z * b4.y; acc[2][2] += a4.z * b4.z; acc[2][3] += a4.z * b4.w;
                acc[3][0] += a4.w * b4.x; acc[3][1] += a4.w * b4.y; acc[3][2] += a4.w * b4.z; acc[3][3] += a4.w * b4.w;
            }
        }
        #pragma unroll
        for (int i = 0; i < 4; ++i) {        // D = sq_q + sq_m - 2*inner
            float sq_q = sqq[(tx << 2) + i];
            float4 dv;
            dv.x = sq_q + sqm[(ty << 2) + 0] - 2.f * acc[i][0];
            dv.y = sq_q + sqm[(ty << 2) + 1] - 2.f * acc[i][1];
            dv.z = sq_q + sqm[(ty << 2) + 2] - 2.f * acc[i][2];
            dv.w = sq_q + sqm[(ty << 2) + 3] - 2.f * acc[i][3];
            *(float4*)&Dt[((tx << 2) + i) * 68 + (ty << 2)] = dv;
        }
        __syncthreads();
        // per-lane top-20 over this tile's subset (r -> 16 columns)
        #pragma unroll 4
        for (int i2 = 0; i2 < 16; ++i2) {
            int mi = (r << 4) + i2;
            float d = Dt[qi * 68 + mi];
            if (d < bd[KNN - 1]) {
                bd[KNN - 1] = d; bi[KNN - 1] = m0 + mi;
                #pragma unroll
                for (int s = KNN - 1; s > 0; --s) {
                    if (bd[s] < bd[s - 1]) {
                        float td = bd[s]; bd[s] = bd[s - 1]; bd[s - 1] = td;
                        int ti = bi[s]; bi[s] = bi[s - 1]; bi[s - 1] = ti;
                    }
                }
            }
        }
    }

    // fp64 refinement: two half-phases (32 queries each) so scratch fits in
    // the Xm/Dt region while Xq stays live.
    __syncthreads();
    double* rD = (double*)(sm + 8192);     // [32][80] doubles = 20480 B
    int*    rI = (int*)(sm + 13312);       // [32][80] ints   = 10240 B
    #pragma unroll 1
    for (int ph = 0; ph < 2; ++ph) {
        if ((qi >> 5) == ph) {
            const int lq = qi & 31;
            #pragma unroll 1
            for (int i = 0; i < KNN; ++i) {
                const int m = bi[i];
                const float* xm = xb + m;
                double d = 0.0;
                #pragma unroll 4
                for (int c = 0; c < CIN; ++c) {
                    double diff = (double)Xq[(c << 6) + qi] - (double)xm[(size_t)c * NPT];
                    d = fma(diff, diff, d);
                }
                rD[lq * 80 + r * KNN + i] = d;
                rI[lq * 80 + r * KNN + i] = m;
            }
        }
        __syncthreads();
        if (t < 32) {
            const int n = q0 + ph * 32 + t;
            int* dst = knn_out + ((size_t)b * NPT + n) * KNN;
            double* Lq = rD + t * 80;
            const int* Li = rI + t * 80;
            #pragma unroll 1
            for (int o = 0; o < KNN; ++o) {
                double best = Lq[0]; int bp = 0;
                #pragma unroll 1
                for (int j2 = 1; j2 < 80; ++j2) {
                    double v = Lq[j2];
                    if (v < best) { best = v; bp = j2; }
                }
                dst[o] = Li[bp];
                Lq[bp] = 1e300;
            }
        }
        __syncthreads();
    }
}

// ------------------------------------------------- BN statistics (pass A)
__global__ __launch_bounds__(256) void stats_kernel(const float* __restrict__ uT,
                                                    const float* __restrict__ vT,
                                                    const int* __restrict__ knn_in,
                                                    double* __restrict__ gsum) {
    __shared__ int sidx[64 * KNN];
    const int b  = blockIdx.y;
    const int n0 = blockIdx.x * 64;
    const int o  = threadIdx.x;
    for (int e = o; e < 64 * KNN; e += 256)
        sidx[e] = knn_in[((size_t)b * NPT + n0) * KNN + e];
    __syncthreads();
    const float* ub = uT + ((size_t)b * NPT + n0) * COUT + o;
    const float* vb = vT + (size_t)b * NPT * COUT + o;
    double s1 = 0.0, s2 = 0.0;
    #pragma unroll 1
    for (int s = 0; s < 64; ++s) {
        float u = ub[(size_t)s * COUT];
        #pragma unroll
        for (int j = 0; j < KNN; ++j) {
            float y = u + vb[(size_t)sidx[s * KNN + j] * COUT];
            s1 += (double)y;
            s2 = fma((double)y, (double)y, s2);
        }
    }
    atomicAdd(&gsum[o], s1);
    atomicAdd(&gsum[COUT + o], s2);
}

// ------------------------------------------------- fold stats -> scale/shift
__global__ void finalize_kernel(const double* __restrict__ gsum,
                                const float* __restrict__ gamma,
                                const float* __restrict__ beta,
                                float* __restrict__ st) {
    const int o = threadIdx.x;
    const double M = (double)B_ * NPT * KNN;
    double mean = gsum[o] / M;
    double var  = gsum[COUT + o] / M - mean * mean;
    float inv = 1.0f / sqrtf((float)var + EPS);
    float s = gamma[o] * inv;
    st[o] = s;
    st[COUT + o] = beta[o] - (float)mean * s;
}

// ------------------------------------------------- gather+affine+relu+max
__global__ __launch_bounds__(256, 2) void out_kernel(const float* __restrict__ uT,
                                                     const float* __restrict__ vT,
                                                     const int* __restrict__ knn_in,
                                                     const float* __restrict__ st,
                                                     float* __restrict__ out) {
    __shared__ int sidx[64 * KNN];
    __shared__ float zt[256 * 68];
    const int b  = blockIdx.y;
    const int n0 = blockIdx.x * 64;
    const int o  = threadIdx.x;
    for (int e = o; e < 64 * KNN; e += 256)
        sidx[e] = knn_in[((size_t)b * NPT + n0) * KNN + e];
    __syncthreads();
    const float s  = st[o];
    const float tt = st[COUT + o];
    const float* ub = uT + ((size_t)b * NPT + n0) * COUT + o;
    const float* vb = vT + (size_t)b * NPT * COUT + o;
    #pragma unroll 1
    for (int si = 0; si < 64; ++si) {
        float u = ub[(size_t)si * COUT];
        float ymax = -3e38f, ymin = 3e38f;
        #pragma unroll
        for (int j = 0; j < KNN; ++j) {
            float y = u + vb[(size_t)sidx[si * KNN + j] * COUT];
            ymax = fmaxf(ymax, y);
            ymin = fminf(ymin, y);
        }
        // max_j relu(s*y+t): argmax of monotone-affine is at ymax (s>=0) or ymin (s<0)
        float z1 = fmaxf(s * ymax + tt, 0.f);
        float z2 = fmaxf(s * ymin + tt, 0.f);
        zt[o * 68 + si] = fmaxf(z1, z2);
    }
    __syncthreads();
    float* dst = out + ((size_t)b * COUT + o) * NPT + n0;
    #pragma unroll
    for (int i = 0; i < 16; ++i)
        *(float4*)&dst[i * 4] = *(const float4*)&zt[o * 68 + i * 4];
}

extern "C" void kernel_launch(void* const* d_in, const int* in_sizes, int n_in,
                              void* d_out, int out_size, void* d_ws, size_t ws_size,
                              hipStream_t stream) {
    const float* x     = (const float*)d_in[0];
    const float* W     = (const float*)d_in[1];
    const float* gamma = (const float*)d_in[2];
    const float* beta  = (const float*)d_in[3];
    float* out = (float*)d_out;
    char* ws = (char*)d_ws;
    float*  sq   = (float*)(ws + SQ_OFF);
    int*    idx  = (int*)(ws + IDX_OFF);
    float*  uT   = (float*)(ws + UT_OFF);
    float*  vT   = (float*)(ws + VT_OFF);
    double* gsum = (double*)(ws + GS_OFF);
    float*  st   = (float*)(ws + ST_OFF);

    hipMemsetAsync(gsum, 0, 2 * COUT * sizeof(double), stream);
    sq_kernel<<<128, 256, 0, stream>>>(x, sq);
    uv_gemm<<<dim3(32, 4, 16), 256, 0, stream>>>(x, W, uT, vT);
    knn_kernel<<<dim3(32, 16), 256, 0, stream>>>(x, sq, idx);
    stats_kernel<<<dim3(32, 16), 256, 0, stream>>>(uT, vT, idx, gsum);
    finalize_kernel<<<1, 256, 0, stream>>>(gsum, gamma, beta, st);
    out_kernel<<<dim3(32, 16), 256, 0, stream>>>(uT, vT, idx, st, out);
}

// Round 2
// 978.089 us; speedup vs baseline: 1.7240x; 1.7240x over previous
//
#include <hip/hip_runtime.h>

#define B_   16
#define CIN  128
#define NPT  2048
#define COUT 256
#define KNN  20
#define EPS  1e-5f

// workspace byte offsets
#define SQ_OFF   0ull                          // 32768 f
#define IDX_OFF  131072ull                     // 16*2048*20 i32
#define UT_OFF   2752512ull                    // 16*2048*256 f
#define VT_OFF   36306944ull                   // 16*2048*256 f
#define GS_OFF   69861376ull                   // 2*256 double
#define ST_OFF   69865472ull                   // 2*256 f
// xT[b][n][c] (16.8 MB) OVERLAPS uT: knn (reads xT) runs BEFORE uv_gemm
// (writes uT) on the serial stream, so the aliasing is safe.
#define XT_OFF   UT_OFF

// ---------------------------------------------------------------- sq[b][n]
__global__ void sq_kernel(const float* __restrict__ x, float* __restrict__ sq) {
    int gid = blockIdx.x * 256 + threadIdx.x;          // 32768 total
    int b = gid >> 11, n = gid & 2047;
    const float* xp = x + (size_t)b * CIN * NPT + n;
    float acc = 0.f;
    #pragma unroll
    for (int c = 0; c < CIN; ++c) { float v = xp[c * NPT]; acc += v * v; }
    sq[gid] = acc;
}

// ------------------------------------------------- xT[b][n][c] = x[b][c][n]
__global__ __launch_bounds__(256) void transpose_kernel(const float* __restrict__ x,
                                                        float* __restrict__ xT) {
    __shared__ float Ls[64 * 65];
    const int b  = blockIdx.z;
    const int n0 = blockIdx.x * 64;
    const int c0 = blockIdx.y * 64;
    const int t  = threadIdx.x;
    const float* xb = x + (size_t)b * CIN * NPT;
    #pragma unroll
    for (int e = 0; e < 16; ++e) {
        int ii = e * 256 + t;
        int cl = ii >> 6, nl = ii & 63;
        Ls[cl * 65 + nl] = xb[(size_t)(c0 + cl) * NPT + n0 + nl];
    }
    __syncthreads();
    #pragma unroll
    for (int e = 0; e < 16; ++e) {
        int ii = e * 256 + t;
        int nl = ii >> 6, cl = ii & 63;
        xT[((size_t)b * NPT + n0 + nl) * CIN + c0 + cl] = Ls[cl * 65 + nl];
    }
}

// ------------------------------------------------- u/v GEMM: uT/vT[b][n][o]
// u = (W1-W2) @ x  (central term), v = W2 @ x (neighbor term)
__global__ __launch_bounds__(256) void uv_gemm(const float* __restrict__ x,
                                               const float* __restrict__ W,
                                               float* __restrict__ uT,
                                               float* __restrict__ vT) {
    __shared__ float Ax[32 * 64];   // [cz][ni]
    __shared__ float Bu[32 * 68];   // [cz][oj], pad 68
    __shared__ float Bv[32 * 68];

    const int b  = blockIdx.z;
    const int n0 = blockIdx.x * 64;
    const int o0 = blockIdx.y * 64;
    const int t  = threadIdx.x;
    const int tx = t & 15, ty = t >> 4;
    const float* xb = x + (size_t)b * CIN * NPT;

    float au[4][4], av_[4][4];
    #pragma unroll
    for (int i = 0; i < 4; ++i)
        #pragma unroll
        for (int j = 0; j < 4; ++j) { au[i][j] = 0.f; av_[i][j] = 0.f; }

    #pragma unroll 1
    for (int kc = 0; kc < 4; ++kc) {
        const int c0 = kc * 32;
        __syncthreads();
        #pragma unroll
        for (int e = 0; e < 2; ++e) {            // x tile: 32c x 64n (float4)
            int f = e * 256 + t;                 // 512 float4s
            int cz = f >> 4, ni = (f & 15) << 2;
            *(float4*)&Ax[(cz << 6) + ni] = *(const float4*)&xb[(size_t)(c0 + cz) * NPT + n0 + ni];
        }
        #pragma unroll
        for (int e = 0; e < 8; ++e) {            // W tiles: 32c x 64o
            int ii = e * 256 + t;
            int cz = ii & 31, oj = ii >> 5;
            float w1 = W[(size_t)(o0 + oj) * 256 + c0 + cz];
            float w2 = W[(size_t)(o0 + oj) * 256 + 128 + c0 + cz];
            Bu[cz * 68 + oj] = w1 - w2;
            Bv[cz * 68 + oj] = w2;
        }
        __syncthreads();
        #pragma unroll 8
        for (int cz = 0; cz < 32; ++cz) {
            const float4 a4 = *(const float4*)&Ax[(cz << 6) + (tx << 2)];
            float bu0 = Bu[cz * 68 + (ty << 2) + 0], bv0 = Bv[cz * 68 + (ty << 2) + 0];
            float bu1 = Bu[cz * 68 + (ty << 2) + 1], bv1 = Bv[cz * 68 + (ty << 2) + 1];
            float bu2 = Bu[cz * 68 + (ty << 2) + 2], bv2 = Bv[cz * 68 + (ty << 2) + 2];
            float bu3 = Bu[cz * 68 + (ty << 2) + 3], bv3 = Bv[cz * 68 + (ty << 2) + 3];
            au[0][0] += a4.x * bu0; au[0][1] += a4.x * bu1; au[0][2] += a4.x * bu2; au[0][3] += a4.x * bu3;
            au[1][0] += a4.y * bu0; au[1][1] += a4.y * bu1; au[1][2] += a4.y * bu2; au[1][3] += a4.y * bu3;
            au[2][0] += a4.z * bu0; au[2][1] += a4.z * bu1; au[2][2] += a4.z * bu2; au[2][3] += a4.z * bu3;
            au[3][0] += a4.w * bu0; au[3][1] += a4.w * bu1; au[3][2] += a4.w * bu2; au[3][3] += a4.w * bu3;
            av_[0][0] += a4.x * bv0; av_[0][1] += a4.x * bv1; av_[0][2] += a4.x * bv2; av_[0][3] += a4.x * bv3;
            av_[1][0] += a4.y * bv0; av_[1][1] += a4.y * bv1; av_[1][2] += a4.y * bv2; av_[1][3] += a4.y * bv3;
            av_[2][0] += a4.z * bv0; av_[2][1] += a4.z * bv1; av_[2][2] += a4.z * bv2; av_[2][3] += a4.z * bv3;
            av_[3][0] += a4.w * bv0; av_[3][1] += a4.w * bv1; av_[3][2] += a4.w * bv2; av_[3][3] += a4.w * bv3;
        }
    }
    #pragma unroll
    for (int i = 0; i < 4; ++i) {
        int n = n0 + (tx << 2) + i;
        size_t base = ((size_t)b * NPT + n) * COUT + o0 + (ty << 2);
        float4 u4 = {au[i][0], au[i][1], au[i][2], au[i][3]};
        float4 v4 = {av_[i][0], av_[i][1], av_[i][2], av_[i][3]};
        *(float4*)&uT[base] = u4;
        *(float4*)&vT[base] = v4;
    }
}

// ---------------------------------------------------------------- KNN
// fp32 tiled distance GEMM + per-lane top-20 (4 lanes/query over disjoint
// m-subsets) + fp64 refinement (coalesced xT rows) -> exact top-20 set.
__global__ __launch_bounds__(256, 2) void knn_kernel(const float* __restrict__ x,
                                                     const float* __restrict__ xT,
                                                     const float* __restrict__ sqn,
                                                     int* __restrict__ knn_out) {
    __shared__ float sm[16768];            // 67072 B
    float* Xq  = sm;                       // [128][64]
    float* Xm  = sm + 8192;                // [64][64]
    float* Dt  = sm + 12288;               // [64][68]
    float* sqq = sm + 16640;               // [64]
    float* sqm = sm + 16704;               // [64]

    const int b  = blockIdx.y;
    const int q0 = blockIdx.x * 64;
    const int t  = threadIdx.x;
    const int tx = t & 15, ty = t >> 4;    // GEMM mapping
    const int qi = t >> 2,  r = t & 3;     // top-k mapping
    const float* xb = x + (size_t)b * CIN * NPT;

    #pragma unroll
    for (int e = 0; e < 8; ++e) {          // Xq: 128c x 64q, float4 staging
        int f = e * 256 + t;               // 2048 float4s
        int c = f >> 4, n4 = (f & 15) << 2;
        *(float4*)&Xq[(c << 6) + n4] = *(const float4*)&xb[(size_t)c * NPT + q0 + n4];
    }
    if (t < 64) sqq[t] = sqn[b * NPT + q0 + t];

    float bd[KNN]; int bi[KNN];
    #pragma unroll
    for (int i = 0; i < KNN; ++i) { bd[i] = 3e38f; bi[i] = 0; }

    #pragma unroll 1
    for (int mt = 0; mt < 32; ++mt) {
        const int m0 = mt * 64;
        float acc[4][4];
        #pragma unroll
        for (int i = 0; i < 4; ++i)
            #pragma unroll
            for (int j = 0; j < 4; ++j) acc[i][j] = 0.f;

        #pragma unroll
        for (int kc = 0; kc < 2; ++kc) {
            __syncthreads();
            #pragma unroll
            for (int e = 0; e < 4; ++e) {   // Xm chunk: 64c x 64m, float4
                int f = e * 256 + t;        // 1024 float4s
                int c = f >> 4, m4 = (f & 15) << 2;
                *(float4*)&Xm[(c << 6) + m4] = *(const float4*)&xb[(size_t)(kc * 64 + c) * NPT + m0 + m4];
            }
            if (kc == 0 && t < 64) sqm[t] = sqn[b * NPT + m0 + t];
            __syncthreads();
            #pragma unroll 8
            for (int c = 0; c < 64; ++c) {
                const float4 a4 = *(const float4*)&Xq[((kc * 64 + c) << 6) + (tx << 2)];
                const float4 b4 = *(const float4*)&Xm[(c << 6) + (ty << 2)];
                acc[0][0] += a4.x * b4.x; acc[0][1] += a4.x * b4.y; acc[0][2] += a4.x * b4.z; acc[0][3] += a4.x * b4.w;
                acc[1][0] += a4.y * b4.x; acc[1][1] += a4.y * b4.y; acc[1][2] += a4.y * b4.z; acc[1][3] += a4.y * b4.w;
                acc[2][0] += a4.z * b4.x; acc[2][1] += a4.z * b4.y; acc[2][2] += a4.z * b4.z; acc[2][3] += a4.z * b4.w;
                acc[3][0] += a4.w * b4.x; acc[3][1] += a4.w * b4.y; acc[3][2] += a4.w * b4.z; acc[3][3] += a4.w * b4.w;
            }
        }
        #pragma unroll
        for (int i = 0; i < 4; ++i) {        // D = sq_q + sq_m - 2*inner
            float sq_q = sqq[(tx << 2) + i];
            float4 dv;
            dv.x = sq_q + sqm[(ty << 2) + 0] - 2.f * acc[i][0];
            dv.y = sq_q + sqm[(ty << 2) + 1] - 2.f * acc[i][1];
            dv.z = sq_q + sqm[(ty << 2) + 2] - 2.f * acc[i][2];
            dv.w = sq_q + sqm[(ty << 2) + 3] - 2.f * acc[i][3];
            *(float4*)&Dt[((tx << 2) + i) * 68 + (ty << 2)] = dv;
        }
        __syncthreads();
        // per-lane top-20 over this tile's subset
        // mi = (i2<<2)+r  -> wave hits all 32 banks 2-way (conflict-free)
        #pragma unroll 4
        for (int i2 = 0; i2 < 16; ++i2) {
            int mi = (i2 << 2) + r;
            float d = Dt[qi * 68 + mi];
            if (d < bd[KNN - 1]) {
                bd[KNN - 1] = d; bi[KNN - 1] = m0 + mi;
                #pragma unroll
                for (int s = KNN - 1; s > 0; --s) {
                    if (bd[s] < bd[s - 1]) {
                        float td = bd[s]; bd[s] = bd[s - 1]; bd[s - 1] = td;
                        int ti = bi[s]; bi[s] = bi[s - 1]; bi[s - 1] = ti;
                    }
                }
            }
        }
    }

    // ---- fp64 refinement, all 256 threads, coalesced xT row reads ----
    double dd[KNN];
    #pragma unroll
    for (int i = 0; i < KNN; ++i) dd[i] = 0.0;
    const float* xTb = xT + (size_t)b * NPT * CIN;
    #pragma unroll 1
    for (int ch = 0; ch < 8; ++ch) {           // 8 chunks of 16 channels
        double qd[16];
        #pragma unroll
        for (int e = 0; e < 16; ++e)
            qd[e] = (double)Xq[((ch * 16 + e) << 6) + qi];
        #pragma unroll
        for (int i = 0; i < KNN; ++i) {
            const float* mrow = xTb + (size_t)bi[i] * CIN + ch * 16;
            float4 ma = *(const float4*)&mrow[0];
            float4 mb = *(const float4*)&mrow[4];
            float4 mc = *(const float4*)&mrow[8];
            float4 md = *(const float4*)&mrow[12];
            double s = dd[i], d0;
            d0 = qd[0]  - (double)ma.x; s = fma(d0, d0, s);
            d0 = qd[1]  - (double)ma.y; s = fma(d0, d0, s);
            d0 = qd[2]  - (double)ma.z; s = fma(d0, d0, s);
            d0 = qd[3]  - (double)ma.w; s = fma(d0, d0, s);
            d0 = qd[4]  - (double)mb.x; s = fma(d0, d0, s);
            d0 = qd[5]  - (double)mb.y; s = fma(d0, d0, s);
            d0 = qd[6]  - (double)mb.z; s = fma(d0, d0, s);
            d0 = qd[7]  - (double)mb.w; s = fma(d0, d0, s);
            d0 = qd[8]  - (double)mc.x; s = fma(d0, d0, s);
            d0 = qd[9]  - (double)mc.y; s = fma(d0, d0, s);
            d0 = qd[10] - (double)mc.z; s = fma(d0, d0, s);
            d0 = qd[11] - (double)mc.w; s = fma(d0, d0, s);
            d0 = qd[12] - (double)md.x; s = fma(d0, d0, s);
            d0 = qd[13] - (double)md.y; s = fma(d0, d0, s);
            d0 = qd[14] - (double)md.z; s = fma(d0, d0, s);
            d0 = qd[15] - (double)md.w; s = fma(d0, d0, s);
            dd[i] = s;
        }
    }

    // ---- exact selection: 2 phases of 32 queries ----
    double* rD = (double*)(sm + 8192);     // [32][80] doubles = 20480 B
    int*    rI = (int*)(sm + 13312);       // [32][80] ints   = 10240 B
    #pragma unroll 1
    for (int ph = 0; ph < 2; ++ph) {
        __syncthreads();                   // protect vs main loop / prev scan
        if ((qi >> 5) == ph) {
            const int lq = qi & 31;
            #pragma unroll
            for (int i = 0; i < KNN; ++i) {
                rD[lq * 80 + r * KNN + i] = dd[i];
                rI[lq * 80 + r * KNN + i] = bi[i];
            }
        }
        __syncthreads();
        if (t < 32) {
            const int n = q0 + ph * 32 + t;
            int* dst = knn_out + ((size_t)b * NPT + n) * KNN;
            double* Lq = rD + t * 80;
            const int* Li = rI + t * 80;
            #pragma unroll 1
            for (int o = 0; o < KNN; ++o) {
                double best = Lq[0]; int bp = 0;
                #pragma unroll 1
                for (int j2 = 1; j2 < 80; ++j2) {
                    double v = Lq[j2];
                    if (v < best) { best = v; bp = j2; }
                }
                dst[o] = Li[bp];
                Lq[bp] = 1e300;
            }
        }
    }
}

// ------------------------------------------------- BN statistics (pass A)
__global__ __launch_bounds__(256) void stats_kernel(const float* __restrict__ uT,
                                                    const float* __restrict__ vT,
                                                    const int* __restrict__ knn_in,
                                                    double* __restrict__ gsum) {
    __shared__ int sidx[64 * KNN];
    const int b  = blockIdx.y;
    const int n0 = blockIdx.x * 64;
    const int o  = threadIdx.x;
    for (int e = o; e < 64 * KNN; e += 256)
        sidx[e] = knn_in[((size_t)b * NPT + n0) * KNN + e];
    __syncthreads();
    const float* ub = uT + ((size_t)b * NPT + n0) * COUT + o;
    const float* vb = vT + (size_t)b * NPT * COUT + o;
    double s1 = 0.0, s2 = 0.0;
    #pragma unroll 1
    for (int s = 0; s < 64; ++s) {
        float u = ub[(size_t)s * COUT];
        #pragma unroll
        for (int j = 0; j < KNN; ++j) {
            float y = u + vb[(size_t)sidx[s * KNN + j] * COUT];
            s1 += (double)y;
            s2 = fma((double)y, (double)y, s2);
        }
    }
    atomicAdd(&gsum[o], s1);
    atomicAdd(&gsum[COUT + o], s2);
}

// ------------------------------------------------- fold stats -> scale/shift
__global__ void finalize_kernel(const double* __restrict__ gsum,
                                const float* __restrict__ gamma,
                                const float* __restrict__ beta,
                                float* __restrict__ st) {
    const int o = threadIdx.x;
    const double M = (double)B_ * NPT * KNN;
    double mean = gsum[o] / M;
    double var  = gsum[COUT + o] / M - mean * mean;
    float inv = 1.0f / sqrtf((float)var + EPS);
    float s = gamma[o] * inv;
    st[o] = s;
    st[COUT + o] = beta[o] - (float)mean * s;
}

// ------------------------------------------------- gather+affine+relu+max
__global__ __launch_bounds__(256, 2) void out_kernel(const float* __restrict__ uT,
                                                     const float* __restrict__ vT,
                                                     const int* __restrict__ knn_in,
                                                     const float* __restrict__ st,
                                                     float* __restrict__ out) {
    __shared__ int sidx[64 * KNN];
    __shared__ float zt[256 * 68];
    const int b  = blockIdx.y;
    const int n0 = blockIdx.x * 64;
    const int o  = threadIdx.x;
    for (int e = o; e < 64 * KNN; e += 256)
        sidx[e] = knn_in[((size_t)b * NPT + n0) * KNN + e];
    __syncthreads();
    const float s  = st[o];
    const float tt = st[COUT + o];
    const float* ub = uT + ((size_t)b * NPT + n0) * COUT + o;
    const float* vb = vT + (size_t)b * NPT * COUT + o;
    #pragma unroll 1
    for (int si = 0; si < 64; ++si) {
        float u = ub[(size_t)si * COUT];
        float ymax = -3e38f, ymin = 3e38f;
        #pragma unroll
        for (int j = 0; j < KNN; ++j) {
            float y = u + vb[(size_t)sidx[si * KNN + j] * COUT];
            ymax = fmaxf(ymax, y);
            ymin = fminf(ymin, y);
        }
        // max_j relu(s*y+t): argmax of monotone-affine is at ymax (s>=0) or ymin (s<0)
        float z1 = fmaxf(s * ymax + tt, 0.f);
        float z2 = fmaxf(s * ymin + tt, 0.f);
        zt[o * 68 + si] = fmaxf(z1, z2);
    }
    __syncthreads();
    float* dst = out + ((size_t)b * COUT + o) * NPT + n0;
    #pragma unroll
    for (int i = 0; i < 16; ++i)
        *(float4*)&dst[i * 4] = *(const float4*)&zt[o * 68 + i * 4];
}

extern "C" void kernel_launch(void* const* d_in, const int* in_sizes, int n_in,
                              void* d_out, int out_size, void* d_ws, size_t ws_size,
                              hipStream_t stream) {
    const float* x     = (const float*)d_in[0];
    const float* W     = (const float*)d_in[1];
    const float* gamma = (const float*)d_in[2];
    const float* beta  = (const float*)d_in[3];
    float* out = (float*)d_out;
    char* ws = (char*)d_ws;
    float*  sq   = (float*)(ws + SQ_OFF);
    int*    idx  = (int*)(ws + IDX_OFF);
    float*  xT   = (float*)(ws + XT_OFF);   // aliases uT region (see note)
    float*  uT   = (float*)(ws + UT_OFF);
    float*  vT   = (float*)(ws + VT_OFF);
    double* gsum = (double*)(ws + GS_OFF);
    float*  st   = (float*)(ws + ST_OFF);

    hipMemsetAsync(gsum, 0, 2 * COUT * sizeof(double), stream);
    sq_kernel<<<128, 256, 0, stream>>>(x, sq);
    transpose_kernel<<<dim3(32, 2, 16), 256, 0, stream>>>(x, xT);
    knn_kernel<<<dim3(32, 16), 256, 0, stream>>>(x, xT, sq, idx);
    // uv_gemm AFTER knn: uT region aliases xT
    uv_gemm<<<dim3(32, 4, 16), 256, 0, stream>>>(x, W, uT, vT);
    stats_kernel<<<dim3(32, 16), 256, 0, stream>>>(uT, vT, idx, gsum);
    finalize_kernel<<<1, 256, 0, stream>>>(gsum, gamma, beta, st);
    out_kernel<<<dim3(32, 16), 256, 0, stream>>>(uT, vT, idx, st, out);
}